// Round 1
// baseline (95.780 us; speedup 1.0000x reference)
//
#include <hip/hip_runtime.h>

#define NPARAMS 21   // 2*DEPTH+1
#define VPT 4        // elements per thread

// Per element: M = S(phi0) * prod_k [ W(x) S(phi_k) ], out = alpha * Re(M[0,0]).
// All factors are SU(2): M = [[a, b], [-conj(b), conj(a)]]. Track a,b only.
// Step: a' = e^{i phi}(c*a + i s*b);  b' = e^{-i phi}(i s*a + c*b),
// with c = cos(x), s = sin(x).
__global__ __launch_bounds__(256) void qsp_kernel(
    const float* __restrict__ x,
    const float* __restrict__ qsp,
    const float* __restrict__ alphas,
    float* __restrict__ out,
    int n)
{
    __shared__ float cph[NPARAMS];
    __shared__ float sph[NPARAMS];
    const int t = threadIdx.x;
    if (t < NPARAMS) {
        float p = qsp[t];
        float sv, cv;
        __sincosf(p, &sv, &cv);
        cph[t] = cv;
        sph[t] = sv;
    }
    __syncthreads();

    const int base = (blockIdx.x * blockDim.x + t) * VPT;
    if (base >= n) return;

    const float4 xv = *reinterpret_cast<const float4*>(x + base);
    const float4 av = *reinterpret_cast<const float4*>(alphas + base);

    float xs[VPT] = {xv.x, xv.y, xv.z, xv.w};
    float al[VPT] = {av.x, av.y, av.z, av.w};

    float c[VPT], s[VPT];
    float ar[VPT], ai[VPT], br[VPT], bi[VPT];

    const float c0 = cph[0];
    const float s0 = sph[0];
#pragma unroll
    for (int j = 0; j < VPT; ++j) {
        __sincosf(xs[j], &s[j], &c[j]);
        ar[j] = c0;  // a = e^{i phi0}
        ai[j] = s0;
        br[j] = 0.0f;
        bi[j] = 0.0f;
    }

#pragma unroll
    for (int k = 1; k < NPARAMS; ++k) {
        const float cp = cph[k];
        const float sp = sph[k];
#pragma unroll
        for (int j = 0; j < VPT; ++j) {
            // t1 = c*a + i s*b ; t2 = i s*a + c*b
            const float t1r = c[j] * ar[j] - s[j] * bi[j];
            const float t1i = c[j] * ai[j] + s[j] * br[j];
            const float t2r = c[j] * br[j] - s[j] * ai[j];
            const float t2i = c[j] * bi[j] + s[j] * ar[j];
            // a' = e^{i phi} t1 ; b' = e^{-i phi} t2
            ar[j] = cp * t1r - sp * t1i;
            ai[j] = cp * t1i + sp * t1r;
            br[j] = cp * t2r + sp * t2i;
            bi[j] = cp * t2i - sp * t2r;
        }
    }

    float4 o;
    o.x = al[0] * ar[0];
    o.y = al[1] * ar[1];
    o.z = al[2] * ar[2];
    o.w = al[3] * ar[3];
    *reinterpret_cast<float4*>(out + base) = o;
}

extern "C" void kernel_launch(void* const* d_in, const int* in_sizes, int n_in,
                              void* d_out, int out_size, void* d_ws, size_t ws_size,
                              hipStream_t stream)
{
    const float* x      = (const float*)d_in[0];
    const float* qsp    = (const float*)d_in[1];
    const float* alphas = (const float*)d_in[2];
    float* out          = (float*)d_out;

    const int n = in_sizes[0];             // 4,000,000 (divisible by 4)
    const int threads = 256;
    const int nthreads = (n + VPT - 1) / VPT;
    const int blocks = (nthreads + threads - 1) / threads;

    qsp_kernel<<<blocks, threads, 0, stream>>>(x, qsp, alphas, out, n);
}

// Round 2
// 84.024 us; speedup vs baseline: 1.1399x; 1.1399x over previous
//
#include <hip/hip_runtime.h>

#define NPARAMS 21      // 2*DEPTH+1 phases
#define VPT 4           // elements per thread in eval kernel
#define INV_2PI 0.15915494309189535f
#define INV_PI  0.3183098861837907f

// Hardware sin/cos take REVOLUTIONS; reduce with v_fract first (periodic, so
// dropping whole revolutions is exact).
__device__ __forceinline__ float sin_rev(float rev) {
    return __builtin_amdgcn_sinf(__builtin_amdgcn_fractf(rev));
}
__device__ __forceinline__ float cos_rev(float rev) {
    return __builtin_amdgcn_cosf(__builtin_amdgcn_fractf(rev));
}

// ---------------------------------------------------------------------------
// Kernel 1: Re(U00(x)) is a trig polynomial of degree 10 in u = 2x:
//   g(u) = P0 + sum_{j=1..10} Pj cos(j u) + Qj sin(j u)
// (20 W-factors -> exponents of e^{ix} are even, |m| <= 20 -> j = m/2 in [-10,10]).
// Sample the exact SU(2) recurrence at u_t = 2*pi*t/21 and invert with the
// exact 21-point real DFT. Writes 24 floats (21 coefs + zero pad) to ws.
// ---------------------------------------------------------------------------
__global__ void coeff_kernel(const float* __restrict__ qsp, float* __restrict__ ws)
{
    __shared__ float g[NPARAMS];
    const int t = threadIdx.x;

    if (t < NPARAMS) {
        // x_t = pi*t/21  ->  revolutions = t/42
        const float rev_x = (float)t * (1.0f / 42.0f);
        const float c = cos_rev(rev_x);
        const float s = sin_rev(rev_x);

        // M = [[a, b], [-conj(b), conj(a)]], start M = S(phi_0)
        float pr = qsp[0] * INV_2PI;
        float ar = cos_rev(pr), ai = sin_rev(pr);
        float br = 0.0f, bi = 0.0f;

        for (int k = 1; k < NPARAMS; ++k) {
            const float pk = qsp[k] * INV_2PI;
            const float cp = cos_rev(pk);
            const float sp = sin_rev(pk);
            // t1 = c*a + i s*b ; t2 = i s*a + c*b
            const float t1r = c * ar - s * bi;
            const float t1i = c * ai + s * br;
            const float t2r = c * br - s * ai;
            const float t2i = c * bi + s * ar;
            // a' = e^{i phi} t1 ; b' = e^{-i phi} t2
            ar = cp * t1r - sp * t1i;
            ai = cp * t1i + sp * t1r;
            br = cp * t2r + sp * t2i;
            bi = cp * t2i - sp * t2r;
        }
        g[t] = ar;   // Re(U00) at sample t
    }
    __syncthreads();

    if (t < 24) {
        float coef = 0.0f;
        if (t == 0) {                       // P0 = mean
            float acc = 0.0f;
            for (int i = 0; i < NPARAMS; ++i) acc += g[i];
            coef = acc * (1.0f / 21.0f);
        } else if (t <= 10) {               // Pj = (2/21) sum g_t cos(j u_t)
            float acc = 0.0f;
            for (int i = 0; i < NPARAMS; ++i)
                acc += g[i] * cos_rev((float)(t * i) * (1.0f / 21.0f));
            coef = acc * (2.0f / 21.0f);
        } else if (t <= 20) {               // Qj = (2/21) sum g_t sin(j u_t)
            const int j = t - 10;
            float acc = 0.0f;
            for (int i = 0; i < NPARAMS; ++i)
                acc += g[i] * sin_rev((float)(j * i) * (1.0f / 21.0f));
            coef = acc * (2.0f / 21.0f);
        }
        ws[t] = coef;                       // ws[21..23] zeroed (float4 pad)
    }
}

// ---------------------------------------------------------------------------
// Kernel 2: per element evaluate
//   out = alpha * ( P0 + sum_{j=1..10} Pj cos(2jx) + Qj sin(2jx) )
// via double-angle (Chebyshev) recurrences from one native sincos of 2x.
// ---------------------------------------------------------------------------
__global__ __launch_bounds__(256) void eval_kernel(
    const float* __restrict__ x,
    const float* __restrict__ alphas,
    const float* __restrict__ coefs,
    float* __restrict__ out,
    int n)
{
    const int base = (blockIdx.x * blockDim.x + threadIdx.x) * VPT;
    if (base >= n) return;

    // coefficient registers (uniform, L1-broadcast float4 loads)
    float w[24];
    {
        const float4* c4 = reinterpret_cast<const float4*>(coefs);
#pragma unroll
        for (int i = 0; i < 6; ++i) {
            const float4 v = c4[i];
            w[4 * i + 0] = v.x; w[4 * i + 1] = v.y;
            w[4 * i + 2] = v.z; w[4 * i + 3] = v.w;
        }
    }
    // w[0] = P0, w[1..10] = P1..P10, w[11..20] = Q1..Q10

    const float4 xv = *reinterpret_cast<const float4*>(x + base);
    const float4 av = *reinterpret_cast<const float4*>(alphas + base);
    const float xs[VPT] = {xv.x, xv.y, xv.z, xv.w};
    const float al[VPT] = {av.x, av.y, av.z, av.w};
    float res[VPT];

#pragma unroll
    for (int j = 0; j < VPT; ++j) {
        // u = 2x -> revolutions = x / pi
        const float f  = __builtin_amdgcn_fractf(xs[j] * INV_PI);
        const float s1 = __builtin_amdgcn_sinf(f);   // sin(2x)
        const float c1 = __builtin_amdgcn_cosf(f);   // cos(2x)
        const float tc = c1 + c1;

        float accP = w[0] + w[1] * c1;               // two accumulators: shorter
        float accQ = w[11] * s1;                     // dependent chains
        float cpp = 1.0f, cp = c1;
        float spp = 0.0f, sp = s1;
#pragma unroll
        for (int k = 2; k <= 10; ++k) {
            const float cn = tc * cp - cpp;          // cos(k u)
            const float sn = tc * sp - spp;          // sin(k u)
            accP += w[k] * cn;
            accQ += w[10 + k] * sn;
            cpp = cp; cp = cn;
            spp = sp; sp = sn;
        }
        res[j] = al[j] * (accP + accQ);
    }

    float4 o;
    o.x = res[0]; o.y = res[1]; o.z = res[2]; o.w = res[3];
    *reinterpret_cast<float4*>(out + base) = o;
}

extern "C" void kernel_launch(void* const* d_in, const int* in_sizes, int n_in,
                              void* d_out, int out_size, void* d_ws, size_t ws_size,
                              hipStream_t stream)
{
    const float* x      = (const float*)d_in[0];
    const float* qsp    = (const float*)d_in[1];
    const float* alphas = (const float*)d_in[2];
    float* out          = (float*)d_out;
    float* wsf          = (float*)d_ws;

    const int n = in_sizes[0];   // 4,000,000 (divisible by VPT)

    coeff_kernel<<<1, 64, 0, stream>>>(qsp, wsf);

    const int threads  = 256;
    const int nthreads = (n + VPT - 1) / VPT;
    const int blocks   = (nthreads + threads - 1) / threads;
    eval_kernel<<<blocks, threads, 0, stream>>>(x, alphas, wsf, out, n);
}

// Round 4
// 83.361 us; speedup vs baseline: 1.1490x; 1.0079x over previous
//
#include <hip/hip_runtime.h>

#define NPARAMS 21      // 2*DEPTH+1 phases
#define INV_2PI 0.15915494309189535f
#define INV_PI  0.3183098861837907f

typedef float v4f __attribute__((ext_vector_type(4)));

// Hardware sin/cos take REVOLUTIONS; v_fract first (exact: integer revolutions drop).
__device__ __forceinline__ float sin_rev(float rev) {
    return __builtin_amdgcn_sinf(__builtin_amdgcn_fractf(rev));
}
__device__ __forceinline__ float cos_rev(float rev) {
    return __builtin_amdgcn_cosf(__builtin_amdgcn_fractf(rev));
}

// ---------------------------------------------------------------------------
// Kernel 1: Re(U00(x)) is a trig polynomial of degree 10 in u = 2x:
//   g(u) = P0 + sum_{j=1..10} Pj cos(j u) + Qj sin(j u)
// Sample the exact SU(2) recurrence at u_t = 2*pi*t/21, invert by exact
// 21-point real DFT. ws[0..10]=P0..P10, ws[11..20]=Q1..Q10, ws[21..23]=0.
// ---------------------------------------------------------------------------
__global__ void coeff_kernel(const float* __restrict__ qsp, float* __restrict__ ws)
{
    __shared__ float g[NPARAMS];
    const int t = threadIdx.x;

    if (t < NPARAMS) {
        // x_t = pi*t/21  ->  revolutions = t/42
        const float rev_x = (float)t * (1.0f / 42.0f);
        const float c = cos_rev(rev_x);
        const float s = sin_rev(rev_x);

        // M = [[a, b], [-conj(b), conj(a)]], start M = S(phi_0)
        float pr = qsp[0] * INV_2PI;
        float ar = cos_rev(pr), ai = sin_rev(pr);
        float br = 0.0f, bi = 0.0f;

        for (int k = 1; k < NPARAMS; ++k) {
            const float pk = qsp[k] * INV_2PI;
            const float cp = cos_rev(pk);
            const float sp = sin_rev(pk);
            const float t1r = c * ar - s * bi;
            const float t1i = c * ai + s * br;
            const float t2r = c * br - s * ai;
            const float t2i = c * bi + s * ar;
            ar = cp * t1r - sp * t1i;
            ai = cp * t1i + sp * t1r;
            br = cp * t2r + sp * t2i;
            bi = cp * t2i - sp * t2r;
        }
        g[t] = ar;   // Re(U00) at sample t
    }
    __syncthreads();

    if (t < 24) {
        float coef = 0.0f;
        if (t == 0) {
            float acc = 0.0f;
            for (int i = 0; i < NPARAMS; ++i) acc += g[i];
            coef = acc * (1.0f / 21.0f);
        } else if (t <= 10) {
            float acc = 0.0f;
            for (int i = 0; i < NPARAMS; ++i)
                acc += g[i] * cos_rev((float)(t * i) * (1.0f / 21.0f));
            coef = acc * (2.0f / 21.0f);
        } else if (t <= 20) {
            const int j = t - 10;
            float acc = 0.0f;
            for (int i = 0; i < NPARAMS; ++i)
                acc += g[i] * sin_rev((float)(j * i) * (1.0f / 21.0f));
            coef = acc * (2.0f / 21.0f);
        }
        ws[t] = coef;
    }
}

// ---------------------------------------------------------------------------
// Kernel 2: out = alpha * (P0 + sum Pj cos(2jx) + Qj sin(2jx)).
// ZERO indexed per-thread arrays: named scalars only (no scratch risk).
// VPT=8, float4 x2 loads, nontemporal vector stores.
// ---------------------------------------------------------------------------
__global__ __launch_bounds__(256) void eval_kernel(
    const float* __restrict__ x,
    const float* __restrict__ alphas,
    const float* __restrict__ coefs,
    float* __restrict__ out,
    int n)
{
    const int base = (blockIdx.x * blockDim.x + threadIdx.x) * 8;
    if (base >= n) return;

    const v4f* c4 = reinterpret_cast<const v4f*>(coefs);
    const v4f k0 = c4[0];  // P0 P1 P2 P3
    const v4f k1 = c4[1];  // P4 P5 P6 P7
    const v4f k2 = c4[2];  // P8 P9 P10 Q1
    const v4f k3 = c4[3];  // Q2 Q3 Q4 Q5
    const v4f k4 = c4[4];  // Q6 Q7 Q8 Q9
    const v4f k5 = c4[5];  // Q10 - - -
    const float P0 = k0.x, P1 = k0.y, P2 = k0.z, P3 = k0.w;
    const float P4 = k1.x, P5 = k1.y, P6 = k1.z, P7 = k1.w;
    const float P8 = k2.x, P9 = k2.y, P10 = k2.z;
    const float Q1 = k2.w, Q2 = k3.x, Q3 = k3.y, Q4 = k3.z, Q5 = k3.w;
    const float Q6 = k4.x, Q7 = k4.y, Q8 = k4.z, Q9 = k4.w, Q10 = k5.x;

    auto eval1 = [&](float xv) -> float {
        const float f  = __builtin_amdgcn_fractf(xv * INV_PI);   // u=2x in revs
        const float s1 = __builtin_amdgcn_sinf(f);
        const float c1 = __builtin_amdgcn_cosf(f);
        const float tc = c1 + c1;
        const float c2  = fmaf(tc, c1, -1.0f);
        const float s2  = tc * s1;
        const float c3  = fmaf(tc, c2, -c1);
        const float s3  = fmaf(tc, s2, -s1);
        const float c4_ = fmaf(tc, c3, -c2);
        const float s4_ = fmaf(tc, s3, -s2);
        const float c5  = fmaf(tc, c4_, -c3);
        const float s5  = fmaf(tc, s4_, -s3);
        const float c6  = fmaf(tc, c5, -c4_);
        const float s6  = fmaf(tc, s5, -s4_);
        const float c7  = fmaf(tc, c6, -c5);
        const float s7  = fmaf(tc, s6, -s5);
        const float c8  = fmaf(tc, c7, -c6);
        const float s8  = fmaf(tc, s7, -s6);
        const float c9  = fmaf(tc, c8, -c7);
        const float s9  = fmaf(tc, s8, -s7);
        const float c10 = fmaf(tc, c9, -c8);
        const float s10 = fmaf(tc, s9, -s8);
        float aP = fmaf(P1, c1, P0);
        float aQ = Q1 * s1;
        aP = fmaf(P2, c2, aP);   aQ = fmaf(Q2, s2, aQ);
        aP = fmaf(P3, c3, aP);   aQ = fmaf(Q3, s3, aQ);
        aP = fmaf(P4, c4_, aP);  aQ = fmaf(Q4, s4_, aQ);
        aP = fmaf(P5, c5, aP);   aQ = fmaf(Q5, s5, aQ);
        aP = fmaf(P6, c6, aP);   aQ = fmaf(Q6, s6, aQ);
        aP = fmaf(P7, c7, aP);   aQ = fmaf(Q7, s7, aQ);
        aP = fmaf(P8, c8, aP);   aQ = fmaf(Q8, s8, aQ);
        aP = fmaf(P9, c9, aP);   aQ = fmaf(Q9, s9, aQ);
        aP = fmaf(P10, c10, aP); aQ = fmaf(Q10, s10, aQ);
        return aP + aQ;
    };

    const v4f* xp = reinterpret_cast<const v4f*>(x + base);
    const v4f* ap = reinterpret_cast<const v4f*>(alphas + base);
    const v4f xa = xp[0], xb = xp[1];
    const v4f aa = ap[0], ab = ap[1];

    v4f oa, ob;
    oa.x = aa.x * eval1(xa.x);
    oa.y = aa.y * eval1(xa.y);
    oa.z = aa.z * eval1(xa.z);
    oa.w = aa.w * eval1(xa.w);
    ob.x = ab.x * eval1(xb.x);
    ob.y = ab.y * eval1(xb.y);
    ob.z = ab.z * eval1(xb.z);
    ob.w = ab.w * eval1(xb.w);

    v4f* op = reinterpret_cast<v4f*>(out + base);
    __builtin_nontemporal_store(oa, op);
    __builtin_nontemporal_store(ob, op + 1);
}

extern "C" void kernel_launch(void* const* d_in, const int* in_sizes, int n_in,
                              void* d_out, int out_size, void* d_ws, size_t ws_size,
                              hipStream_t stream)
{
    const float* x      = (const float*)d_in[0];
    const float* qsp    = (const float*)d_in[1];
    const float* alphas = (const float*)d_in[2];
    float* out          = (float*)d_out;
    float* wsf          = (float*)d_ws;

    const int n = in_sizes[0];   // 4,000,000 (divisible by 8)

    coeff_kernel<<<1, 64, 0, stream>>>(qsp, wsf);

    const int threads  = 256;
    const int nthreads = (n + 7) / 8;
    const int blocks   = (nthreads + threads - 1) / threads;
    eval_kernel<<<blocks, threads, 0, stream>>>(x, alphas, wsf, out, n);
}

// Round 5
// 82.797 us; speedup vs baseline: 1.1568x; 1.0068x over previous
//
#include <hip/hip_runtime.h>

#define NPARAMS 21      // 2*DEPTH+1 phases
#define INV_2PI 0.15915494309189535f
#define INV_PI  0.3183098861837907f

typedef float v4f __attribute__((ext_vector_type(4)));

// Hardware sin/cos take REVOLUTIONS; v_fract first (exact: integer revolutions drop).
__device__ __forceinline__ float sin_rev(float rev) {
    return __builtin_amdgcn_sinf(__builtin_amdgcn_fractf(rev));
}
__device__ __forceinline__ float cos_rev(float rev) {
    return __builtin_amdgcn_cosf(__builtin_amdgcn_fractf(rev));
}

// ---------------------------------------------------------------------------
// Single fused kernel.
//
// Math: Re(U00(x)) is a trig polynomial of degree 10 in u = 2x:
//   g(u) = P0 + sum_{j=1..10} Pj cos(j u) + Qj sin(j u)
// (20 SU(2) W-factors -> even exponents of e^{ix}, |m| <= 20.)
// Each block redundantly recovers P/Q: lanes 0..20 run the exact SU(2)
// recurrence at samples u_t = 2*pi*t/21, then invert with the exact 21-point
// real DFT into LDS (~300 serial ops, hidden by ~8 resident blocks/CU).
// Then all threads evaluate via Chebyshev double-angle recurrences, VPT=8.
// ---------------------------------------------------------------------------
__global__ __launch_bounds__(256) void qsp_fused_kernel(
    const float* __restrict__ x,
    const float* __restrict__ qsp,
    const float* __restrict__ alphas,
    float* __restrict__ out,
    int n)
{
    __shared__ float g[NPARAMS];
    __shared__ float coef[NPARAMS];
    const int t = threadIdx.x;

    if (t < NPARAMS) {
        // x_t = pi*t/21  ->  revolutions = t/42
        const float rev_x = (float)t * (1.0f / 42.0f);
        const float c = cos_rev(rev_x);
        const float s = sin_rev(rev_x);

        // M = [[a, b], [-conj(b), conj(a)]], start M = S(phi_0)
        float pr = qsp[0] * INV_2PI;
        float ar = cos_rev(pr), ai = sin_rev(pr);
        float br = 0.0f, bi = 0.0f;

        for (int k = 1; k < NPARAMS; ++k) {
            const float pk = qsp[k] * INV_2PI;
            const float cp = cos_rev(pk);
            const float sp = sin_rev(pk);
            const float t1r = c * ar - s * bi;
            const float t1i = c * ai + s * br;
            const float t2r = c * br - s * ai;
            const float t2i = c * bi + s * ar;
            ar = cp * t1r - sp * t1i;
            ai = cp * t1i + sp * t1r;
            br = cp * t2r + sp * t2i;
            bi = cp * t2i - sp * t2r;
        }
        g[t] = ar;   // Re(U00) at sample t
    }
    __syncthreads();

    if (t < NPARAMS) {
        float acc = 0.0f;
        if (t == 0) {
            for (int i = 0; i < NPARAMS; ++i) acc += g[i];
            acc *= (1.0f / 21.0f);
        } else if (t <= 10) {                       // Pj
            for (int i = 0; i < NPARAMS; ++i)
                acc += g[i] * cos_rev((float)(t * i) * (1.0f / 21.0f));
            acc *= (2.0f / 21.0f);
        } else {                                    // Qj, j = t-10
            const int j = t - 10;
            for (int i = 0; i < NPARAMS; ++i)
                acc += g[i] * sin_rev((float)(j * i) * (1.0f / 21.0f));
            acc *= (2.0f / 21.0f);
        }
        coef[t] = acc;
    }
    __syncthreads();

    // Broadcast LDS reads (all lanes same address -> conflict-free).
    const float P0 = coef[0],  P1 = coef[1],  P2 = coef[2],  P3 = coef[3];
    const float P4 = coef[4],  P5 = coef[5],  P6 = coef[6],  P7 = coef[7];
    const float P8 = coef[8],  P9 = coef[9],  P10 = coef[10];
    const float Q1 = coef[11], Q2 = coef[12], Q3 = coef[13], Q4 = coef[14];
    const float Q5 = coef[15], Q6 = coef[16], Q7 = coef[17], Q8 = coef[18];
    const float Q9 = coef[19], Q10 = coef[20];

    const int base = (blockIdx.x * blockDim.x + t) * 8;
    if (base >= n) return;

    auto eval1 = [&](float xv) -> float {
        const float f  = __builtin_amdgcn_fractf(xv * INV_PI);   // u=2x in revs
        const float s1 = __builtin_amdgcn_sinf(f);
        const float c1 = __builtin_amdgcn_cosf(f);
        const float tc = c1 + c1;
        const float c2  = fmaf(tc, c1, -1.0f);
        const float s2  = tc * s1;
        const float c3  = fmaf(tc, c2, -c1);
        const float s3  = fmaf(tc, s2, -s1);
        const float c4_ = fmaf(tc, c3, -c2);
        const float s4_ = fmaf(tc, s3, -s2);
        const float c5  = fmaf(tc, c4_, -c3);
        const float s5  = fmaf(tc, s4_, -s3);
        const float c6  = fmaf(tc, c5, -c4_);
        const float s6  = fmaf(tc, s5, -s4_);
        const float c7  = fmaf(tc, c6, -c5);
        const float s7  = fmaf(tc, s6, -s5);
        const float c8  = fmaf(tc, c7, -c6);
        const float s8  = fmaf(tc, s7, -s6);
        const float c9  = fmaf(tc, c8, -c7);
        const float s9  = fmaf(tc, s8, -s7);
        const float c10 = fmaf(tc, c9, -c8);
        const float s10 = fmaf(tc, s9, -s8);
        float aP = fmaf(P1, c1, P0);
        float aQ = Q1 * s1;
        aP = fmaf(P2, c2, aP);   aQ = fmaf(Q2, s2, aQ);
        aP = fmaf(P3, c3, aP);   aQ = fmaf(Q3, s3, aQ);
        aP = fmaf(P4, c4_, aP);  aQ = fmaf(Q4, s4_, aQ);
        aP = fmaf(P5, c5, aP);   aQ = fmaf(Q5, s5, aQ);
        aP = fmaf(P6, c6, aP);   aQ = fmaf(Q6, s6, aQ);
        aP = fmaf(P7, c7, aP);   aQ = fmaf(Q7, s7, aQ);
        aP = fmaf(P8, c8, aP);   aQ = fmaf(Q8, s8, aQ);
        aP = fmaf(P9, c9, aP);   aQ = fmaf(Q9, s9, aQ);
        aP = fmaf(P10, c10, aP); aQ = fmaf(Q10, s10, aQ);
        return aP + aQ;
    };

    const v4f* xp = reinterpret_cast<const v4f*>(x + base);
    const v4f* ap = reinterpret_cast<const v4f*>(alphas + base);
    const v4f xa = xp[0], xb = xp[1];
    const v4f aa = ap[0], ab = ap[1];

    v4f oa, ob;
    oa.x = aa.x * eval1(xa.x);
    oa.y = aa.y * eval1(xa.y);
    oa.z = aa.z * eval1(xa.z);
    oa.w = aa.w * eval1(xa.w);
    ob.x = ab.x * eval1(xb.x);
    ob.y = ab.y * eval1(xb.y);
    ob.z = ab.z * eval1(xb.z);
    ob.w = ab.w * eval1(xb.w);

    v4f* op = reinterpret_cast<v4f*>(out + base);
    __builtin_nontemporal_store(oa, op);
    __builtin_nontemporal_store(ob, op + 1);
}

extern "C" void kernel_launch(void* const* d_in, const int* in_sizes, int n_in,
                              void* d_out, int out_size, void* d_ws, size_t ws_size,
                              hipStream_t stream)
{
    const float* x      = (const float*)d_in[0];
    const float* qsp    = (const float*)d_in[1];
    const float* alphas = (const float*)d_in[2];
    float* out          = (float*)d_out;

    const int n = in_sizes[0];   // 4,000,000 (divisible by 8)

    const int threads  = 256;
    const int nthreads = (n + 7) / 8;
    const int blocks   = (nthreads + threads - 1) / threads;
    qsp_fused_kernel<<<blocks, threads, 0, stream>>>(x, qsp, alphas, out, n);
}